// Round 8
// baseline (321.501 us; speedup 1.0000x reference)
//
#include <hip/hip_runtime.h>

#define DMODEL 768
#define NHEADS 12
#define MAXFULL 16

typedef __attribute__((ext_vector_type(8))) short short8;
typedef __attribute__((ext_vector_type(4))) float f32x4;

__device__ __forceinline__ unsigned pack2_bf16(float a, float b) {
  unsigned ua = __float_as_uint(a), ub = __float_as_uint(b);
  ua = (ua + 0x7fffu + ((ua >> 16) & 1u)) >> 16;
  ub = (ub + 0x7fffu + ((ub >> 16) & 1u)) & 0xffff0000u;
  return ua | ub;
}
__device__ __forceinline__ unsigned short bf16_1(float a) {
  unsigned ua = __float_as_uint(a);
  return (unsigned short)((ua + 0x7fffu + ((ua >> 16) & 1u)) >> 16);
}

// convert the 4 weight matrices f32 -> bf16 once
__global__ __launch_bounds__(256) void convW(const float* __restrict__ w0,
    const float* __restrict__ w1, const float* __restrict__ w2,
    const float* __restrict__ w3, unsigned* __restrict__ o0,
    unsigned* __restrict__ o1, unsigned* __restrict__ o2,
    unsigned* __restrict__ o3, int count) {  // count = elems per matrix
  const int nv = count >> 2;                 // float4s per matrix
  const float* src[4] = {w0, w1, w2, w3};
  unsigned* dst[4] = {o0, o1, o2, o3};
  for (int idx = blockIdx.x * 256 + threadIdx.x; idx < 4 * nv;
       idx += gridDim.x * 256) {
    int m = idx / nv, r = idx - m * nv;
    float4 v = ((const float4*)src[m])[r];
    dst[m][2 * r]     = pack2_bf16(v.x, v.y);
    dst[m][2 * r + 1] = pack2_bf16(v.z, v.w);
  }
}

// C[M,768] = A[M,768] @ W^T + bias. W pre-converted bf16 [col][k].
// A is f32 (converted during LDS staging) or bf16. MFMA 16x16x32 bf16.
// 128x128 tile, BK=32, 4 waves x (4x4 frags).
// Register-prefetch pipeline: iter k+1 global loads issue right after the
// first barrier, overlapping the MFMA section and the second barrier.
// XCD swizzle: flat blockIdx round-robins XCDs (id&7); all nbx column-tiles
// of one row-tile map to the same XCD so A is HBM-fetched once and W stays
// hot in that XCD's L2. Requires (M/128) % 8 == 0.
template<int A_F32>
__global__ __launch_bounds__(256) void gemm_mfma(const void* __restrict__ Ap,
    const unsigned short* __restrict__ Wb, const float* __restrict__ bias,
    const int* __restrict__ row_map, float* __restrict__ C, int M, int nbx) {
  __shared__ unsigned short As[128 * 40];  // row stride 40 (80B): 2-way = free
  __shared__ unsigned short Bs[128 * 40];
  const int t = threadIdx.x;
  const int id = blockIdx.x;
  const int xcd = id & 7, j = id >> 3;
  const int bn = (j % nbx) * 128;
  const int bm = ((j / nbx) * 8 + xcd) * 128;
  const int lane = t & 63, wid = t >> 6;
  const int m16 = lane & 15, quad = lane >> 4;
  const int wm = (wid >> 1) * 64, wn = (wid & 1) * 64;

  f32x4 acc[4][4];
#pragma unroll
  for (int i = 0; i < 4; ++i)
#pragma unroll
    for (int j2 = 0; j2 < 4; ++j2) acc[i][j2] = (f32x4){0.f, 0.f, 0.f, 0.f};

  const int srow = t >> 1, skc = (t & 1) * 16;
  const int am = bm + srow;
  const bool amok = am < M;
  const int arow = amok ? (row_map ? row_map[am] : am) : 0;
  const int wrow = bn + srow;  // < 768 always
  const float* Af = (const float*)Ap;
  const unsigned short* Ab = (const unsigned short*)Ap;

  float4 fa[4];      // f32-A prefetch regs
  uint4 ab[2];       // bf16-A prefetch regs
  uint4 wp[2];       // W prefetch regs

  auto prefetch = [&](int k0) {
    if (A_F32) {
      if (amok) {
        const float4* pa = (const float4*)(Af + (size_t)arow * DMODEL + k0 + skc);
        fa[0] = pa[0]; fa[1] = pa[1]; fa[2] = pa[2]; fa[3] = pa[3];
      } else {
        fa[0] = fa[1] = fa[2] = fa[3] = make_float4(0.f, 0.f, 0.f, 0.f);
      }
    } else {
      if (amok) {
        const uint4* pa = (const uint4*)(Ab + (size_t)arow * DMODEL + k0 + skc);
        ab[0] = pa[0]; ab[1] = pa[1];
      } else {
        ab[0] = make_uint4(0, 0, 0, 0); ab[1] = make_uint4(0, 0, 0, 0);
      }
    }
    const uint4* pw = (const uint4*)(Wb + (size_t)wrow * DMODEL + k0 + skc);
    wp[0] = pw[0]; wp[1] = pw[1];
  };

  prefetch(0);
  for (int k0 = 0; k0 < DMODEL; k0 += 32) {
    // stage prefetched regs -> LDS (vmcnt wait lands here, not at issue site)
    uint4 aw0, aw1;
    if (A_F32) {
      aw0 = make_uint4(pack2_bf16(fa[0].x, fa[0].y), pack2_bf16(fa[0].z, fa[0].w),
                       pack2_bf16(fa[1].x, fa[1].y), pack2_bf16(fa[1].z, fa[1].w));
      aw1 = make_uint4(pack2_bf16(fa[2].x, fa[2].y), pack2_bf16(fa[2].z, fa[2].w),
                       pack2_bf16(fa[3].x, fa[3].y), pack2_bf16(fa[3].z, fa[3].w));
    } else {
      aw0 = ab[0]; aw1 = ab[1];
    }
    *(uint4*)&As[srow * 40 + skc]     = aw0;
    *(uint4*)&As[srow * 40 + skc + 8] = aw1;
    *(uint4*)&Bs[srow * 40 + skc]     = wp[0];
    *(uint4*)&Bs[srow * 40 + skc + 8] = wp[1];
    __syncthreads();
    int kn = k0 + 32;
    if (kn >= DMODEL) kn = 0;      // harmless L2-hit reload on last iter
    prefetch(kn);                  // overlaps MFMA below + bottom barrier
    short8 a[4], b[4];
#pragma unroll
    for (int i = 0; i < 4; ++i)
      a[i] = *(const short8*)&As[(wm + i * 16 + m16) * 40 + quad * 8];
#pragma unroll
    for (int j2 = 0; j2 < 4; ++j2)
      b[j2] = *(const short8*)&Bs[(wn + j2 * 16 + m16) * 40 + quad * 8];
#pragma unroll
    for (int i = 0; i < 4; ++i)
#pragma unroll
      for (int j2 = 0; j2 < 4; ++j2)
        acc[i][j2] = __builtin_amdgcn_mfma_f32_16x16x32_bf16(a[i], b[j2], acc[i][j2], 0, 0, 0);
    __syncthreads();
  }

  // epilogue: C/D layout col=lane&15, row=quad*4+r (m89/m91)
  float bv[4]; int bcol[4];
#pragma unroll
  for (int j2 = 0; j2 < 4; ++j2) {
    bcol[j2] = bn + wn + j2 * 16 + m16;
    bv[j2] = bias[bcol[j2]];
  }
#pragma unroll
  for (int i = 0; i < 4; ++i) {
    const int rbase = bm + wm + i * 16 + quad * 4;
#pragma unroll
    for (int r = 0; r < 4; ++r) {
      const int row = rbase + r;
      if (row < M) {
#pragma unroll
        for (int j2 = 0; j2 < 4; ++j2)
          C[(size_t)row * DMODEL + bcol[j2]] = acc[i][j2][r] + bv[j2];
      }
    }
  }
}

// one block: prefix-scan query_mask -> left/right/nvalid per feature,
// plus compact list of fully-masked features (nvalid==0).
__global__ __launch_bounds__(1024) void build_segments(const int* __restrict__ qm,
    const int* __restrict__ ids, const int* __restrict__ padp,
    int n, int f, int* __restrict__ left, int* __restrict__ right,
    int* __restrict__ nvalid, int* __restrict__ fullrank,
    int* __restrict__ fullist, int* __restrict__ nfull) {
  __shared__ int cnt[1024];
  __shared__ int fullcnt;
  const int t = threadIdx.x;
  if (t == 0) fullcnt = 0;
  const int per = (n + 1023) >> 10;
  const int base = t * per;
  int c = 0;
  for (int i = 0; i < per; ++i) {
    int p = base + i;
    if (p < n && qm[p] != 0) ++c;
  }
  cnt[t] = c;
  __syncthreads();
  for (int off = 1; off < 1024; off <<= 1) {
    int v = (t >= off) ? cnt[t - off] : 0;
    __syncthreads();
    cnt[t] += v;
    __syncthreads();
  }
  int r = cnt[t] - c;  // exclusive prefix
  for (int i = 0; i < per; ++i) {
    int p = base + i;
    if (p < n && qm[p] != 0) {
      if (r < f) left[r] = p;
      ++r;
    }
  }
  __syncthreads();
  const int pad = *padp;
  for (int i = t; i < f; i += 1024) {
    int L0 = left[i];
    int R0 = (i + 1 < f) ? left[i + 1] : n;
    right[i] = R0;
    int cv = 0;
    for (int p = L0; p < R0; ++p) cv += (ids[p] != pad) ? 1 : 0;
    nvalid[i] = cv;
    if (cv == 0) {
      int rk = atomicAdd(&fullcnt, 1);
      if (rk < MAXFULL) { fullist[rk] = i; fullrank[i] = rk; }
      else fullrank[i] = -1;
    } else {
      fullrank[i] = -1;
    }
  }
  __syncthreads();
  if (t == 0) *nfull = (fullcnt < MAXFULL) ? fullcnt : MAXFULL;
}

__device__ __forceinline__ float allreduce64(float x) {
#pragma unroll
  for (int m = 1; m < 64; m <<= 1) x += __shfl_xor(x, m, 64);
  return x;
}

// normal features: online softmax over the (short) segment, skipping pad keys.
// Out-of-segment/pad contributions underflow to exact 0 in the reference's f32
// softmax, so segment-only is exact. Writes bf16 (input to the Wo GEMM).
__global__ __launch_bounds__(64) void attn_seg(const float* __restrict__ q,
    const float* __restrict__ k, const float* __restrict__ v,
    const int* __restrict__ left, const int* __restrict__ right,
    const int* __restrict__ nvalid, const int* __restrict__ ids,
    const int* __restrict__ padp, unsigned short* __restrict__ out) {
  const int feat = blockIdx.x, h = blockIdx.y, lane = threadIdx.x;
  if (nvalid[feat] == 0) return;  // handled by attn_full_*
  const int off = h * 64 + lane;
  const int pad = *padp;
  const float qv = q[(size_t)feat * DMODEL + off];
  float m = -1e30f, l = 0.f, acc = 0.f;
  const int L0 = left[feat], R0 = right[feat];
  for (int p = L0; p < R0; ++p) {
    if (ids[p] == pad) continue;
    float s = allreduce64(qv * k[(size_t)p * DMODEL + off]) * 0.125f;
    float mn = fmaxf(m, s);
    float al = __expf(m - mn);
    float w = __expf(s - mn);
    l = l * al + w;
    acc = acc * al + w * v[(size_t)p * DMODEL + off];
    m = mn;
  }
  out[(size_t)feat * DMODEL + off] = bf16_1(acc / l);
}

// fully-masked features: uniform -10000 bias cancels in softmax -> full softmax
// over ALL n keys (pads included, cross-batch).
// One wave per (head, 64-key piece); lane=key for QK (streamed in-lane dot vs
// all q's staged in LDS), lane=dim for PV (weights via aligned LDS b128).
__global__ __launch_bounds__(256) void attn_full_part(const float* __restrict__ q,
    const float* __restrict__ k, const float* __restrict__ v,
    const int* __restrict__ fullist, const int* __restrict__ nfullp,
    int n, int P, float* __restrict__ pm, float* __restrict__ pl,
    float* __restrict__ pacc) {
  const int nfull = *nfullp;
  if (nfull == 0) return;
  const int t = threadIdx.x, lane = t & 63, wv = t >> 6;
  const int gw = blockIdx.x * 4 + wv;     // P % 4 == 0 -> block-uniform head
  const int h = gw / P, piece = gw - h * P;
  const int pk = n / P;                    // keys per piece (multiple of 64)

  __shared__ float q_lds[8 * 64];
  __shared__ float w_lds[4][64 * 8];       // [wave][key][feat], 32B-aligned rows

  for (int idx = t; idx < 8 * 64; idx += 256) {
    int fl = idx >> 6, d = idx & 63;
    q_lds[idx] = (fl < nfull) ? q[(size_t)fullist[fl] * DMODEL + h * 64 + d] : 0.f;
  }
  __syncthreads();

  float m[8], l[8], acc[8];
#pragma unroll
  for (int f_ = 0; f_ < 8; ++f_) { m[f_] = -1e30f; l[f_] = 0.f; acc[f_] = 0.f; }

  for (int c = 0; c < pk; c += 64) {
    const int pc = piece * pk + c;
    // ---- phase A: lane = key. Stream k in two 8-float4 groups (no kv[16]).
    float s[8];
#pragma unroll
    for (int f_ = 0; f_ < 8; ++f_) s[f_] = 0.f;
    const float4* kp = (const float4*)(k + (size_t)(pc + lane) * DMODEL + h * 64);
#pragma unroll 1
    for (int g = 0; g < 2; ++g) {
      float4 kv0 = kp[g * 8 + 0], kv1 = kp[g * 8 + 1], kv2 = kp[g * 8 + 2],
             kv3 = kp[g * 8 + 3], kv4 = kp[g * 8 + 4], kv5 = kp[g * 8 + 5],
             kv6 = kp[g * 8 + 6], kv7 = kp[g * 8 + 7];
      const float4* qb = (const float4*)&q_lds[g * 32];
#pragma unroll
      for (int f_ = 0; f_ < 8; ++f_) {
        float4 q0 = qb[f_ * 16 + 0], q1 = qb[f_ * 16 + 1], q2 = qb[f_ * 16 + 2],
               q3 = qb[f_ * 16 + 3], q4 = qb[f_ * 16 + 4], q5 = qb[f_ * 16 + 5],
               q6 = qb[f_ * 16 + 6], q7 = qb[f_ * 16 + 7];
        float acc0 = q0.x * kv0.x + q0.y * kv0.y + q0.z * kv0.z + q0.w * kv0.w;
        acc0 += q1.x * kv1.x + q1.y * kv1.y + q1.z * kv1.z + q1.w * kv1.w;
        acc0 += q2.x * kv2.x + q2.y * kv2.y + q2.z * kv2.z + q2.w * kv2.w;
        acc0 += q3.x * kv3.x + q3.y * kv3.y + q3.z * kv3.z + q3.w * kv3.w;
        acc0 += q4.x * kv4.x + q4.y * kv4.y + q4.z * kv4.z + q4.w * kv4.w;
        acc0 += q5.x * kv5.x + q5.y * kv5.y + q5.z * kv5.z + q5.w * kv5.w;
        acc0 += q6.x * kv6.x + q6.y * kv6.y + q6.z * kv6.z + q6.w * kv6.w;
        acc0 += q7.x * kv7.x + q7.y * kv7.y + q7.z * kv7.z + q7.w * kv7.w;
        s[f_] += acc0;
      }
    }
    // batched reductions: 8 independent chains interleave per step
    float mx[8];
#pragma unroll
    for (int f_ = 0; f_ < 8; ++f_) mx[f_] = s[f_] * 0.125f;
#pragma unroll
    for (int f_ = 0; f_ < 8; ++f_) s[f_] = mx[f_];
#pragma unroll
    for (int st = 1; st < 64; st <<= 1)
#pragma unroll
      for (int f_ = 0; f_ < 8; ++f_) mx[f_] = fmaxf(mx[f_], __shfl_xor(mx[f_], st, 64));
    float alpha[8], w[8], sum[8];
#pragma unroll
    for (int f_ = 0; f_ < 8; ++f_) {
      float mn = fmaxf(m[f_], mx[f_]);
      alpha[f_] = __expf(m[f_] - mn);
      w[f_] = __expf(s[f_] - mn);
      m[f_] = mn;
      sum[f_] = w[f_];
    }
#pragma unroll
    for (int st = 1; st < 64; st <<= 1)
#pragma unroll
      for (int f_ = 0; f_ < 8; ++f_) sum[f_] += __shfl_xor(sum[f_], st, 64);
#pragma unroll
    for (int f_ = 0; f_ < 8; ++f_) l[f_] = l[f_] * alpha[f_] + sum[f_];
    // two aligned b128 stores (intra-wave LDS: hw orders ds ops in program order)
    *(float4*)&w_lds[wv][lane * 8]     = make_float4(w[0], w[1], w[2], w[3]);
    *(float4*)&w_lds[wv][lane * 8 + 4] = make_float4(w[4], w[5], w[6], w[7]);
    // ---- phase B: lane = dim
#pragma unroll
    for (int f_ = 0; f_ < 8; ++f_) acc[f_] *= alpha[f_];
    const float* vb = v + (size_t)pc * DMODEL + h * 64 + lane;
#pragma unroll 4
    for (int kk = 0; kk < 64; ++kk) {
      float vd = vb[(size_t)kk * DMODEL];
      float4 wa = *(const float4*)&w_lds[wv][kk * 8];      // broadcast b128
      float4 wb = *(const float4*)&w_lds[wv][kk * 8 + 4];
      acc[0] += wa.x * vd; acc[1] += wa.y * vd; acc[2] += wa.z * vd; acc[3] += wa.w * vd;
      acc[4] += wb.x * vd; acc[5] += wb.y * vd; acc[6] += wb.z * vd; acc[7] += wb.w * vd;
    }
  }

  for (int f_ = 0; f_ < nfull; ++f_) {
    size_t idx = ((size_t)f_ * NHEADS + h) * P + piece;
    if (lane == 0) { pm[idx] = m[f_]; pl[idx] = l[f_]; }
    pacc[idx * 64 + lane] = acc[f_];
  }
}

// Split-K pass 2: merge the P partials per (full-feature, head).
// One block (256 thr) per (fl, h): parallel block reductions. Writes bf16.
__global__ __launch_bounds__(256) void attn_full_comb(
    const int* __restrict__ fullist, const int* __restrict__ nfullp,
    int P, const float* __restrict__ pm, const float* __restrict__ pl,
    const float* __restrict__ pacc, unsigned short* __restrict__ out) {
  const int fl = blockIdx.x, h = blockIdx.y;
  if (fl >= *nfullp) return;
  const int feat = fullist[fl];
  const int t = threadIdx.x, lane = t & 63, wv = t >> 6;
  const size_t base = ((size_t)fl * NHEADS + h) * P;

  __shared__ float s_pm[128];    // P <= 128
  __shared__ float s_sc[128];
  __shared__ float s_red[4];
  __shared__ float s_part[4][64];

  for (int sp = t; sp < P; sp += 256) s_pm[sp] = pm[base + sp];
  __syncthreads();
  // block max of pm
  float mloc = -1e30f;
  for (int sp = t; sp < P; sp += 256) mloc = fmaxf(mloc, s_pm[sp]);
#pragma unroll
  for (int st = 1; st < 64; st <<= 1) mloc = fmaxf(mloc, __shfl_xor(mloc, st, 64));
  if (lane == 0) s_red[wv] = mloc;
  __syncthreads();
  const float M = fmaxf(fmaxf(s_red[0], s_red[1]), fmaxf(s_red[2], s_red[3]));
  __syncthreads();  // everyone has M before s_red reuse
  // scale factors + Lt
  float lloc = 0.f;
  for (int sp = t; sp < P; sp += 256) {
    float sc = __expf(s_pm[sp] - M);
    s_sc[sp] = sc;
    lloc += pl[base + sp] * sc;
  }
#pragma unroll
  for (int st = 1; st < 64; st <<= 1) lloc += __shfl_xor(lloc, st, 64);
  if (lane == 0) s_red[wv] = lloc;
  __syncthreads();
  const float Lt = s_red[0] + s_red[1] + s_red[2] + s_red[3];
  // weighted acc: wave wv takes sp = wv, wv+4, ... (independent coalesced loads)
  float At = 0.f;
  for (int sp = wv; sp < P; sp += 4)
    At += pacc[(base + sp) * 64 + lane] * s_sc[sp];
  s_part[wv][lane] = At;
  __syncthreads();
  if (wv == 0) {
    float tot = s_part[0][lane] + s_part[1][lane] + s_part[2][lane] + s_part[3][lane];
    out[(size_t)feat * DMODEL + h * 64 + lane] = bf16_1(tot / Lt);
  }
}

extern "C" void kernel_launch(void* const* d_in, const int* in_sizes, int n_in,
                              void* d_out, int out_size, void* d_ws, size_t ws_size,
                              hipStream_t stream) {
  const float* x_qk = (const float*)d_in[0];
  const float* x_v  = (const float*)d_in[1];
  const int* qm     = (const int*)d_in[2];
  const int* ids    = (const int*)d_in[3];
  const int* padp   = (const int*)d_in[4];
  const float* Wq = (const float*)d_in[5];
  const float* bq = (const float*)d_in[6];
  const float* Wk = (const float*)d_in[7];
  const float* bk = (const float*)d_in[8];
  const float* Wv = (const float*)d_in[9];
  const float* bv = (const float*)d_in[10];
  const float* Wo = (const float*)d_in[11];
  const float* bo = (const float*)d_in[12];

  const int n = in_sizes[0] / DMODEL;   // 8192
  const int f = out_size / DMODEL;      // 1024

  // ws layout: kf,vf,qf f32 | af bf16 | Wbf x4 | ints | split partials
  float* kf = (float*)d_ws;
  float* vf = kf + (size_t)n * DMODEL;
  float* qf = vf + (size_t)n * DMODEL;
  unsigned short* af = (unsigned short*)(qf + (size_t)f * DMODEL);
  unsigned short* wqb = af + (size_t)f * DMODEL;
  unsigned short* wkb = wqb + DMODEL * DMODEL;
  unsigned short* wvb = wkb + DMODEL * DMODEL;
  unsigned short* wob = wvb + DMODEL * DMODEL;
  int* left     = (int*)(wob + DMODEL * DMODEL);
  int* right    = left + f;
  int* nvalid   = right + f;
  int* fullrank = nvalid + f;
  int* fullist  = fullrank + f;
  int* nfull    = fullist + MAXFULL;
  size_t off_bytes = ((size_t)((char*)(nfull + 1) - (char*)d_ws) + 255) & ~(size_t)255;
  // pieces of 64 keys each: P waves per head; pk = n/P must be a multiple of 64
  int P = 128;
  while (P > 16) {
    size_t need = (size_t)MAXFULL * NHEADS * P * 66 * sizeof(float);
    if (off_bytes + need <= ws_size && (n / P) % 64 == 0 && n % P == 0) break;
    P >>= 1;
  }
  float* pm = (float*)((char*)d_ws + off_bytes);
  float* pl = pm + (size_t)MAXFULL * NHEADS * P;
  float* pacc = pl + (size_t)MAXFULL * NHEADS * P;

  build_segments<<<1, 1024, 0, stream>>>(qm, ids, padp, n, f, left, right,
                                         nvalid, fullrank, fullist, nfull);
  convW<<<1152, 256, 0, stream>>>(Wq, Wk, Wv, Wo, (unsigned*)wqb, (unsigned*)wkb,
                                  (unsigned*)wvb, (unsigned*)wob, DMODEL * DMODEL);

  const int TKV = 6 * (n / 128);   // 384 blocks, (n/128)%8==0
  const int TF  = 6 * (f / 128);   // 48 blocks,  (f/128)%8==0
  gemm_mfma<1><<<TKV, 256, 0, stream>>>(x_qk, wkb, bk, nullptr, kf, n, 6);
  gemm_mfma<1><<<TKV, 256, 0, stream>>>(x_v,  wvb, bv, nullptr, vf, n, 6);
  gemm_mfma<1><<<TF,  256, 0, stream>>>(x_qk, wqb, bq, left,    qf, f, 6);

  attn_seg<<<dim3(f, NHEADS), 64, 0, stream>>>(qf, kf, vf, left, right, nvalid,
                                               ids, padp, af);
  attn_full_part<<<NHEADS * P / 4, 256, 0, stream>>>(qf, kf, vf, fullist, nfull,
                                                     n, P, pm, pl, pacc);
  attn_full_comb<<<dim3(MAXFULL, NHEADS), 256, 0, stream>>>(fullist, nfull, P,
                                                            pm, pl, pacc, af);

  gemm_mfma<0><<<TF, 256, 0, stream>>>(af, wob, bo, nullptr, (float*)d_out, f, 6);
}

// Round 9
// 267.133 us; speedup vs baseline: 1.2035x; 1.2035x over previous
//
#include <hip/hip_runtime.h>

#define DMODEL 768
#define NHEADS 12
#define MAXFULL 16

typedef __attribute__((ext_vector_type(8))) short short8;
typedef __attribute__((ext_vector_type(4))) float f32x4;

__device__ __forceinline__ unsigned pack2_bf16(float a, float b) {
  unsigned ua = __float_as_uint(a), ub = __float_as_uint(b);
  ua = (ua + 0x7fffu + ((ua >> 16) & 1u)) >> 16;
  ub = (ub + 0x7fffu + ((ub >> 16) & 1u)) & 0xffff0000u;
  return ua | ub;
}
__device__ __forceinline__ unsigned short bf16_1(float a) {
  unsigned ua = __float_as_uint(a);
  return (unsigned short)((ua + 0x7fffu + ((ua >> 16) & 1u)) >> 16);
}

// convert the 4 weight matrices f32 -> bf16 once
__global__ __launch_bounds__(256) void convW(const float* __restrict__ w0,
    const float* __restrict__ w1, const float* __restrict__ w2,
    const float* __restrict__ w3, unsigned* __restrict__ o0,
    unsigned* __restrict__ o1, unsigned* __restrict__ o2,
    unsigned* __restrict__ o3, int count) {  // count = elems per matrix
  const int nv = count >> 2;                 // float4s per matrix
  const float* src[4] = {w0, w1, w2, w3};
  unsigned* dst[4] = {o0, o1, o2, o3};
  for (int idx = blockIdx.x * 256 + threadIdx.x; idx < 4 * nv;
       idx += gridDim.x * 256) {
    int m = idx / nv, r = idx - m * nv;
    float4 v = ((const float4*)src[m])[r];
    dst[m][2 * r]     = pack2_bf16(v.x, v.y);
    dst[m][2 * r + 1] = pack2_bf16(v.z, v.w);
  }
}

// C[M,768] = A[M,768] @ W^T + bias. W pre-converted bf16 [col][k].
// A is f32 (converted during LDS staging) or bf16. MFMA 16x16x32 bf16.
// 64x128 tile, BK=32, 4 waves (2x2) x (2x4 frags) — small tile => 2x more
// blocks => ~3 blocks/CU so load latency hides across independent blocks
// (R8 post-mortem: cross-barrier reg-prefetch is defeated by the vmcnt(0)
// drain __syncthreads emits; TLP is the lever that works at this size).
// XCD swizzle (kept from R8: FETCH 76->18 MB): id&7 spreads row-tiles over
// XCDs; all nbx column-tiles of one row-tile are dispatch-adjacent.
// Requires (M/64) % 8 == 0.
template<int A_F32>
__global__ __launch_bounds__(256) void gemm_mfma(const void* __restrict__ Ap,
    const unsigned short* __restrict__ Wb, const float* __restrict__ bias,
    const int* __restrict__ row_map, float* __restrict__ C, int M, int nbx) {
  __shared__ unsigned short As[64 * 40];   // row stride 40 (80B): 2-way = free
  __shared__ unsigned short Bs[128 * 40];
  const int t = threadIdx.x;
  const int id = blockIdx.x;
  const int xcd = id & 7, j = id >> 3;
  const int bn = (j % nbx) * 128;
  const int bm = ((j / nbx) * 8 + xcd) * 64;
  const int lane = t & 63, wid = t >> 6;
  const int m16 = lane & 15, quad = lane >> 4;
  const int wm = (wid & 1) * 32, wn = (wid >> 1) * 64;

  f32x4 acc[2][4];
#pragma unroll
  for (int i = 0; i < 2; ++i)
#pragma unroll
    for (int j2 = 0; j2 < 4; ++j2) acc[i][j2] = (f32x4){0.f, 0.f, 0.f, 0.f};

  // A staging: thread t loads 8 k-elems of row t>>2 at k-offset (t&3)*8
  // B staging: thread t loads 16 k-elems of row t>>1 at k-offset (t&1)*16
  const int srowA = t >> 2, skcA = (t & 3) * 8;
  const int srowB = t >> 1, skcB = (t & 1) * 16;
  const int am = bm + srowA;
  const bool amok = am < M;
  const int arow = amok ? (row_map ? row_map[am] : am) : 0;
  const int wrow = bn + srowB;  // < 768 always
  const float* Af = (const float*)Ap;
  const unsigned short* Ab = (const unsigned short*)Ap;

  for (int k0 = 0; k0 < DMODEL; k0 += 32) {
    uint4 aw;
    if (A_F32) {
      if (amok) {
        const float4* pa = (const float4*)(Af + (size_t)arow * DMODEL + k0 + skcA);
        float4 f0 = pa[0], f1 = pa[1];
        aw = make_uint4(pack2_bf16(f0.x, f0.y), pack2_bf16(f0.z, f0.w),
                        pack2_bf16(f1.x, f1.y), pack2_bf16(f1.z, f1.w));
      } else {
        aw = make_uint4(0, 0, 0, 0);
      }
    } else {
      if (amok) aw = *(const uint4*)(Ab + (size_t)arow * DMODEL + k0 + skcA);
      else      aw = make_uint4(0, 0, 0, 0);
    }
    const uint4* pw = (const uint4*)(Wb + (size_t)wrow * DMODEL + k0 + skcB);
    uint4 w0 = pw[0], w1 = pw[1];
    *(uint4*)&As[srowA * 40 + skcA]     = aw;
    *(uint4*)&Bs[srowB * 40 + skcB]     = w0;
    *(uint4*)&Bs[srowB * 40 + skcB + 8] = w1;
    __syncthreads();
    short8 a[2], b[4];
#pragma unroll
    for (int i = 0; i < 2; ++i)
      a[i] = *(const short8*)&As[(wm + i * 16 + m16) * 40 + quad * 8];
#pragma unroll
    for (int j2 = 0; j2 < 4; ++j2)
      b[j2] = *(const short8*)&Bs[(wn + j2 * 16 + m16) * 40 + quad * 8];
#pragma unroll
    for (int i = 0; i < 2; ++i)
#pragma unroll
      for (int j2 = 0; j2 < 4; ++j2)
        acc[i][j2] = __builtin_amdgcn_mfma_f32_16x16x32_bf16(a[i], b[j2], acc[i][j2], 0, 0, 0);
    __syncthreads();
  }

  // epilogue: C/D layout col=lane&15, row=quad*4+r (m89/m91)
  float bv[4]; int bcol[4];
#pragma unroll
  for (int j2 = 0; j2 < 4; ++j2) {
    bcol[j2] = bn + wn + j2 * 16 + m16;
    bv[j2] = bias[bcol[j2]];
  }
#pragma unroll
  for (int i = 0; i < 2; ++i) {
    const int rbase = bm + wm + i * 16 + quad * 4;
#pragma unroll
    for (int r = 0; r < 4; ++r) {
      const int row = rbase + r;
      if (row < M) {
#pragma unroll
        for (int j2 = 0; j2 < 4; ++j2)
          C[(size_t)row * DMODEL + bcol[j2]] = acc[i][j2][r] + bv[j2];
      }
    }
  }
}

// one block: prefix-scan query_mask -> left/right/nvalid per feature,
// plus compact list of fully-masked features (nvalid==0).
__global__ __launch_bounds__(1024) void build_segments(const int* __restrict__ qm,
    const int* __restrict__ ids, const int* __restrict__ padp,
    int n, int f, int* __restrict__ left, int* __restrict__ right,
    int* __restrict__ nvalid, int* __restrict__ fullrank,
    int* __restrict__ fullist, int* __restrict__ nfull) {
  __shared__ int cnt[1024];
  __shared__ int fullcnt;
  const int t = threadIdx.x;
  if (t == 0) fullcnt = 0;
  const int per = (n + 1023) >> 10;
  const int base = t * per;
  int c = 0;
  for (int i = 0; i < per; ++i) {
    int p = base + i;
    if (p < n && qm[p] != 0) ++c;
  }
  cnt[t] = c;
  __syncthreads();
  for (int off = 1; off < 1024; off <<= 1) {
    int v = (t >= off) ? cnt[t - off] : 0;
    __syncthreads();
    cnt[t] += v;
    __syncthreads();
  }
  int r = cnt[t] - c;  // exclusive prefix
  for (int i = 0; i < per; ++i) {
    int p = base + i;
    if (p < n && qm[p] != 0) {
      if (r < f) left[r] = p;
      ++r;
    }
  }
  __syncthreads();
  const int pad = *padp;
  for (int i = t; i < f; i += 1024) {
    int L0 = left[i];
    int R0 = (i + 1 < f) ? left[i + 1] : n;
    right[i] = R0;
    int cv = 0;
    for (int p = L0; p < R0; ++p) cv += (ids[p] != pad) ? 1 : 0;
    nvalid[i] = cv;
    if (cv == 0) {
      int rk = atomicAdd(&fullcnt, 1);
      if (rk < MAXFULL) { fullist[rk] = i; fullrank[i] = rk; }
      else fullrank[i] = -1;
    } else {
      fullrank[i] = -1;
    }
  }
  __syncthreads();
  if (t == 0) *nfull = (fullcnt < MAXFULL) ? fullcnt : MAXFULL;
}

__device__ __forceinline__ float allreduce64(float x) {
#pragma unroll
  for (int m = 1; m < 64; m <<= 1) x += __shfl_xor(x, m, 64);
  return x;
}

// normal features: online softmax over the (short) segment, skipping pad keys.
// Out-of-segment/pad contributions underflow to exact 0 in the reference's f32
// softmax, so segment-only is exact. Writes bf16 (input to the Wo GEMM).
__global__ __launch_bounds__(64) void attn_seg(const float* __restrict__ q,
    const float* __restrict__ k, const float* __restrict__ v,
    const int* __restrict__ left, const int* __restrict__ right,
    const int* __restrict__ nvalid, const int* __restrict__ ids,
    const int* __restrict__ padp, unsigned short* __restrict__ out) {
  const int feat = blockIdx.x, h = blockIdx.y, lane = threadIdx.x;
  if (nvalid[feat] == 0) return;  // handled by attn_full_*
  const int off = h * 64 + lane;
  const int pad = *padp;
  const float qv = q[(size_t)feat * DMODEL + off];
  float m = -1e30f, l = 0.f, acc = 0.f;
  const int L0 = left[feat], R0 = right[feat];
  for (int p = L0; p < R0; ++p) {
    if (ids[p] == pad) continue;
    float s = allreduce64(qv * k[(size_t)p * DMODEL + off]) * 0.125f;
    float mn = fmaxf(m, s);
    float al = __expf(m - mn);
    float w = __expf(s - mn);
    l = l * al + w;
    acc = acc * al + w * v[(size_t)p * DMODEL + off];
    m = mn;
  }
  out[(size_t)feat * DMODEL + off] = bf16_1(acc / l);
}

// fully-masked features: uniform -10000 bias cancels in softmax -> full softmax
// over ALL n keys (pads included, cross-batch).
// One wave per (head, 64-key piece); lane=key for QK (streamed in-lane dot vs
// all q's staged in LDS), lane=dim for PV (weights via aligned LDS b128).
__global__ __launch_bounds__(256) void attn_full_part(const float* __restrict__ q,
    const float* __restrict__ k, const float* __restrict__ v,
    const int* __restrict__ fullist, const int* __restrict__ nfullp,
    int n, int P, float* __restrict__ pm, float* __restrict__ pl,
    float* __restrict__ pacc) {
  const int nfull = *nfullp;
  if (nfull == 0) return;
  const int t = threadIdx.x, lane = t & 63, wv = t >> 6;
  const int gw = blockIdx.x * 4 + wv;     // P % 4 == 0 -> block-uniform head
  const int h = gw / P, piece = gw - h * P;
  const int pk = n / P;                    // keys per piece (multiple of 64)

  __shared__ float q_lds[8 * 64];
  __shared__ float w_lds[4][64 * 8];       // [wave][key][feat], 32B-aligned rows

  for (int idx = t; idx < 8 * 64; idx += 256) {
    int fl = idx >> 6, d = idx & 63;
    q_lds[idx] = (fl < nfull) ? q[(size_t)fullist[fl] * DMODEL + h * 64 + d] : 0.f;
  }
  __syncthreads();

  float m[8], l[8], acc[8];
#pragma unroll
  for (int f_ = 0; f_ < 8; ++f_) { m[f_] = -1e30f; l[f_] = 0.f; acc[f_] = 0.f; }

  for (int c = 0; c < pk; c += 64) {
    const int pc = piece * pk + c;
    // ---- phase A: lane = key. Stream k in two 8-float4 groups (no kv[16]).
    float s[8];
#pragma unroll
    for (int f_ = 0; f_ < 8; ++f_) s[f_] = 0.f;
    const float4* kp = (const float4*)(k + (size_t)(pc + lane) * DMODEL + h * 64);
#pragma unroll 1
    for (int g = 0; g < 2; ++g) {
      float4 kv0 = kp[g * 8 + 0], kv1 = kp[g * 8 + 1], kv2 = kp[g * 8 + 2],
             kv3 = kp[g * 8 + 3], kv4 = kp[g * 8 + 4], kv5 = kp[g * 8 + 5],
             kv6 = kp[g * 8 + 6], kv7 = kp[g * 8 + 7];
      const float4* qb = (const float4*)&q_lds[g * 32];
#pragma unroll
      for (int f_ = 0; f_ < 8; ++f_) {
        float4 q0 = qb[f_ * 16 + 0], q1 = qb[f_ * 16 + 1], q2 = qb[f_ * 16 + 2],
               q3 = qb[f_ * 16 + 3], q4 = qb[f_ * 16 + 4], q5 = qb[f_ * 16 + 5],
               q6 = qb[f_ * 16 + 6], q7 = qb[f_ * 16 + 7];
        float acc0 = q0.x * kv0.x + q0.y * kv0.y + q0.z * kv0.z + q0.w * kv0.w;
        acc0 += q1.x * kv1.x + q1.y * kv1.y + q1.z * kv1.z + q1.w * kv1.w;
        acc0 += q2.x * kv2.x + q2.y * kv2.y + q2.z * kv2.z + q2.w * kv2.w;
        acc0 += q3.x * kv3.x + q3.y * kv3.y + q3.z * kv3.z + q3.w * kv3.w;
        acc0 += q4.x * kv4.x + q4.y * kv4.y + q4.z * kv4.z + q4.w * kv4.w;
        acc0 += q5.x * kv5.x + q5.y * kv5.y + q5.z * kv5.z + q5.w * kv5.w;
        acc0 += q6.x * kv6.x + q6.y * kv6.y + q6.z * kv6.z + q6.w * kv6.w;
        acc0 += q7.x * kv7.x + q7.y * kv7.y + q7.z * kv7.z + q7.w * kv7.w;
        s[f_] += acc0;
      }
    }
    // batched reductions: 8 independent chains interleave per step
    float mx[8];
#pragma unroll
    for (int f_ = 0; f_ < 8; ++f_) mx[f_] = s[f_] * 0.125f;
#pragma unroll
    for (int f_ = 0; f_ < 8; ++f_) s[f_] = mx[f_];
#pragma unroll
    for (int st = 1; st < 64; st <<= 1)
#pragma unroll
      for (int f_ = 0; f_ < 8; ++f_) mx[f_] = fmaxf(mx[f_], __shfl_xor(mx[f_], st, 64));
    float alpha[8], w[8], sum[8];
#pragma unroll
    for (int f_ = 0; f_ < 8; ++f_) {
      float mn = fmaxf(m[f_], mx[f_]);
      alpha[f_] = __expf(m[f_] - mn);
      w[f_] = __expf(s[f_] - mn);
      m[f_] = mn;
      sum[f_] = w[f_];
    }
#pragma unroll
    for (int st = 1; st < 64; st <<= 1)
#pragma unroll
      for (int f_ = 0; f_ < 8; ++f_) sum[f_] += __shfl_xor(sum[f_], st, 64);
#pragma unroll
    for (int f_ = 0; f_ < 8; ++f_) l[f_] = l[f_] * alpha[f_] + sum[f_];
    // two aligned b128 stores (intra-wave LDS: hw orders ds ops in program order)
    *(float4*)&w_lds[wv][lane * 8]     = make_float4(w[0], w[1], w[2], w[3]);
    *(float4*)&w_lds[wv][lane * 8 + 4] = make_float4(w[4], w[5], w[6], w[7]);
    // ---- phase B: lane = dim
#pragma unroll
    for (int f_ = 0; f_ < 8; ++f_) acc[f_] *= alpha[f_];
    const float* vb = v + (size_t)pc * DMODEL + h * 64 + lane;
#pragma unroll 4
    for (int kk = 0; kk < 64; ++kk) {
      float vd = vb[(size_t)kk * DMODEL];
      float4 wa = *(const float4*)&w_lds[wv][kk * 8];      // broadcast b128
      float4 wb = *(const float4*)&w_lds[wv][kk * 8 + 4];
      acc[0] += wa.x * vd; acc[1] += wa.y * vd; acc[2] += wa.z * vd; acc[3] += wa.w * vd;
      acc[4] += wb.x * vd; acc[5] += wb.y * vd; acc[6] += wb.z * vd; acc[7] += wb.w * vd;
    }
  }

  for (int f_ = 0; f_ < nfull; ++f_) {
    size_t idx = ((size_t)f_ * NHEADS + h) * P + piece;
    if (lane == 0) { pm[idx] = m[f_]; pl[idx] = l[f_]; }
    pacc[idx * 64 + lane] = acc[f_];
  }
}

// Split-K pass 2: merge the P partials per (full-feature, head).
// One block (256 thr) per (fl, h): parallel block reductions. Writes bf16.
__global__ __launch_bounds__(256) void attn_full_comb(
    const int* __restrict__ fullist, const int* __restrict__ nfullp,
    int P, const float* __restrict__ pm, const float* __restrict__ pl,
    const float* __restrict__ pacc, unsigned short* __restrict__ out) {
  const int fl = blockIdx.x, h = blockIdx.y;
  if (fl >= *nfullp) return;
  const int feat = fullist[fl];
  const int t = threadIdx.x, lane = t & 63, wv = t >> 6;
  const size_t base = ((size_t)fl * NHEADS + h) * P;

  __shared__ float s_pm[128];    // P <= 128
  __shared__ float s_sc[128];
  __shared__ float s_red[4];
  __shared__ float s_part[4][64];

  for (int sp = t; sp < P; sp += 256) s_pm[sp] = pm[base + sp];
  __syncthreads();
  // block max of pm
  float mloc = -1e30f;
  for (int sp = t; sp < P; sp += 256) mloc = fmaxf(mloc, s_pm[sp]);
#pragma unroll
  for (int st = 1; st < 64; st <<= 1) mloc = fmaxf(mloc, __shfl_xor(mloc, st, 64));
  if (lane == 0) s_red[wv] = mloc;
  __syncthreads();
  const float M = fmaxf(fmaxf(s_red[0], s_red[1]), fmaxf(s_red[2], s_red[3]));
  __syncthreads();  // everyone has M before s_red reuse
  // scale factors + Lt
  float lloc = 0.f;
  for (int sp = t; sp < P; sp += 256) {
    float sc = __expf(s_pm[sp] - M);
    s_sc[sp] = sc;
    lloc += pl[base + sp] * sc;
  }
#pragma unroll
  for (int st = 1; st < 64; st <<= 1) lloc += __shfl_xor(lloc, st, 64);
  if (lane == 0) s_red[wv] = lloc;
  __syncthreads();
  const float Lt = s_red[0] + s_red[1] + s_red[2] + s_red[3];
  // weighted acc: wave wv takes sp = wv, wv+4, ... (independent coalesced loads)
  float At = 0.f;
  for (int sp = wv; sp < P; sp += 4)
    At += pacc[(base + sp) * 64 + lane] * s_sc[sp];
  s_part[wv][lane] = At;
  __syncthreads();
  if (wv == 0) {
    float tot = s_part[0][lane] + s_part[1][lane] + s_part[2][lane] + s_part[3][lane];
    out[(size_t)feat * DMODEL + h * 64 + lane] = bf16_1(tot / Lt);
  }
}

extern "C" void kernel_launch(void* const* d_in, const int* in_sizes, int n_in,
                              void* d_out, int out_size, void* d_ws, size_t ws_size,
                              hipStream_t stream) {
  const float* x_qk = (const float*)d_in[0];
  const float* x_v  = (const float*)d_in[1];
  const int* qm     = (const int*)d_in[2];
  const int* ids    = (const int*)d_in[3];
  const int* padp   = (const int*)d_in[4];
  const float* Wq = (const float*)d_in[5];
  const float* bq = (const float*)d_in[6];
  const float* Wk = (const float*)d_in[7];
  const float* bk = (const float*)d_in[8];
  const float* Wv = (const float*)d_in[9];
  const float* bv = (const float*)d_in[10];
  const float* Wo = (const float*)d_in[11];
  const float* bo = (const float*)d_in[12];

  const int n = in_sizes[0] / DMODEL;   // 8192
  const int f = out_size / DMODEL;      // 1024

  // ws layout: kf,vf,qf f32 | af bf16 | Wbf x4 | ints | split partials
  float* kf = (float*)d_ws;
  float* vf = kf + (size_t)n * DMODEL;
  float* qf = vf + (size_t)n * DMODEL;
  unsigned short* af = (unsigned short*)(qf + (size_t)f * DMODEL);
  unsigned short* wqb = af + (size_t)f * DMODEL;
  unsigned short* wkb = wqb + DMODEL * DMODEL;
  unsigned short* wvb = wkb + DMODEL * DMODEL;
  unsigned short* wob = wvb + DMODEL * DMODEL;
  int* left     = (int*)(wob + DMODEL * DMODEL);
  int* right    = left + f;
  int* nvalid   = right + f;
  int* fullrank = nvalid + f;
  int* fullist  = fullrank + f;
  int* nfull    = fullist + MAXFULL;
  size_t off_bytes = ((size_t)((char*)(nfull + 1) - (char*)d_ws) + 255) & ~(size_t)255;
  // pieces of 64 keys each: P waves per head; pk = n/P must be a multiple of 64
  int P = 128;
  while (P > 16) {
    size_t need = (size_t)MAXFULL * NHEADS * P * 66 * sizeof(float);
    if (off_bytes + need <= ws_size && (n / P) % 64 == 0 && n % P == 0) break;
    P >>= 1;
  }
  float* pm = (float*)((char*)d_ws + off_bytes);
  float* pl = pm + (size_t)MAXFULL * NHEADS * P;
  float* pacc = pl + (size_t)MAXFULL * NHEADS * P;

  build_segments<<<1, 1024, 0, stream>>>(qm, ids, padp, n, f, left, right,
                                         nvalid, fullrank, fullist, nfull);
  convW<<<1152, 256, 0, stream>>>(Wq, Wk, Wv, Wo, (unsigned*)wqb, (unsigned*)wkb,
                                  (unsigned*)wvb, (unsigned*)wob, DMODEL * DMODEL);

  const int TKV = 6 * (n / 64);   // 768 blocks, (n/64)%8==0
  const int TF  = 6 * (f / 64);   // 96 blocks,  (f/64)%8==0
  gemm_mfma<1><<<TKV, 256, 0, stream>>>(x_qk, wkb, bk, nullptr, kf, n, 6);
  gemm_mfma<1><<<TKV, 256, 0, stream>>>(x_v,  wvb, bv, nullptr, vf, n, 6);
  gemm_mfma<1><<<TF,  256, 0, stream>>>(x_qk, wqb, bq, left,    qf, f, 6);

  attn_seg<<<dim3(f, NHEADS), 64, 0, stream>>>(qf, kf, vf, left, right, nvalid,
                                               ids, padp, af);
  attn_full_part<<<NHEADS * P / 4, 256, 0, stream>>>(qf, kf, vf, fullist, nfull,
                                                     n, P, pm, pl, pacc);
  attn_full_comb<<<dim3(MAXFULL, NHEADS), 256, 0, stream>>>(fullist, nfull, P,
                                                            pm, pl, pacc, af);

  gemm_mfma<0><<<TF, 256, 0, stream>>>(af, wob, bo, nullptr, (float*)d_out, f, 6);
}

// Round 11
// 242.061 us; speedup vs baseline: 1.3282x; 1.1036x over previous
//
#include <hip/hip_runtime.h>

#define DMODEL 768
#define NHEADS 12
#define MAXFULL 16

typedef __attribute__((ext_vector_type(8))) short short8;
typedef __attribute__((ext_vector_type(4))) float f32x4;

__device__ __forceinline__ unsigned pack2_bf16(float a, float b) {
  unsigned ua = __float_as_uint(a), ub = __float_as_uint(b);
  ua = (ua + 0x7fffu + ((ua >> 16) & 1u)) >> 16;
  ub = (ub + 0x7fffu + ((ub >> 16) & 1u)) & 0xffff0000u;
  return ua | ub;
}
__device__ __forceinline__ unsigned short bf16_1(float a) {
  unsigned ua = __float_as_uint(a);
  return (unsigned short)((ua + 0x7fffu + ((ua >> 16) & 1u)) >> 16);
}

// convert the 4 weight matrices f32 -> bf16 once
__global__ __launch_bounds__(256) void convW(const float* __restrict__ w0,
    const float* __restrict__ w1, const float* __restrict__ w2,
    const float* __restrict__ w3, unsigned* __restrict__ o0,
    unsigned* __restrict__ o1, unsigned* __restrict__ o2,
    unsigned* __restrict__ o3, int count) {  // count = elems per matrix
  const int nv = count >> 2;                 // float4s per matrix
  const float* src[4] = {w0, w1, w2, w3};
  unsigned* dst[4] = {o0, o1, o2, o3};
  for (int idx = blockIdx.x * 256 + threadIdx.x; idx < 4 * nv;
       idx += gridDim.x * 256) {
    int m = idx / nv, r = idx - m * nv;
    float4 v = ((const float4*)src[m])[r];
    dst[m][2 * r]     = pack2_bf16(v.x, v.y);
    dst[m][2 * r + 1] = pack2_bf16(v.z, v.w);
  }
}

struct GDesc {
  const float* A;                 // f32 activations [*,768]
  const unsigned short* W;        // bf16 weights [col][k]
  const float* bias;
  const int* row_map;             // optional row gather
  float* C;                       // f32 out [M,768]
  int M;
  int base;                       // first flat block id of this segment (mult of 8)
};

// Three independent GEMMs (k, v, q) fused into ONE dispatch for TLP:
// R9 post-mortem — each 64x128-tile GEMM alone caps at 3 blocks/CU and is
// latency-bound (MfmaUtil 8%, HBM 1 TB/s); fusing triples resident blocks.
// Per segment: 64x128 tile, BK=32, 4 waves (2x2)x(2x4 frags), XCD swizzle
// (segment bases % 8 == 0 so global id&7 == local id&7).
__global__ __launch_bounds__(256) void gemm_mfma3(GDesc g0, GDesc g1, GDesc g2) {
  __shared__ unsigned short As[64 * 40];   // row stride 40 (80B): 2-way = free
  __shared__ unsigned short Bs[128 * 40];
  const int t = threadIdx.x;
  const int id = blockIdx.x;
  const GDesc& d = (id >= g2.base) ? g2 : ((id >= g1.base) ? g1 : g0);
  const int lid = id - d.base;
  const int xcd = lid & 7, j = lid >> 3;
  const int bn = (j % 6) * 128;
  const int bm = ((j / 6) * 8 + xcd) * 64;
  const int lane = t & 63, wid = t >> 6;
  const int m16 = lane & 15, quad = lane >> 4;
  const int wm = (wid & 1) * 32, wn = (wid >> 1) * 64;

  f32x4 acc[2][4];
#pragma unroll
  for (int i = 0; i < 2; ++i)
#pragma unroll
    for (int j2 = 0; j2 < 4; ++j2) acc[i][j2] = (f32x4){0.f, 0.f, 0.f, 0.f};

  const int srowA = t >> 2, skcA = (t & 3) * 8;
  const int srowB = t >> 1, skcB = (t & 1) * 16;
  const int am = bm + srowA;
  const bool amok = am < d.M;
  const int arow = amok ? (d.row_map ? d.row_map[am] : am) : 0;
  const int wrow = bn + srowB;  // < 768 always
  const float* Af = d.A;

  for (int k0 = 0; k0 < DMODEL; k0 += 32) {
    uint4 aw;
    if (amok) {
      const float4* pa = (const float4*)(Af + (size_t)arow * DMODEL + k0 + skcA);
      float4 f0 = pa[0], f1 = pa[1];
      aw = make_uint4(pack2_bf16(f0.x, f0.y), pack2_bf16(f0.z, f0.w),
                      pack2_bf16(f1.x, f1.y), pack2_bf16(f1.z, f1.w));
    } else {
      aw = make_uint4(0, 0, 0, 0);
    }
    const uint4* pw = (const uint4*)(d.W + (size_t)wrow * DMODEL + k0 + skcB);
    uint4 w0 = pw[0], w1 = pw[1];
    *(uint4*)&As[srowA * 40 + skcA]     = aw;
    *(uint4*)&Bs[srowB * 40 + skcB]     = w0;
    *(uint4*)&Bs[srowB * 40 + skcB + 8] = w1;
    __syncthreads();
    short8 a[2], b[4];
#pragma unroll
    for (int i = 0; i < 2; ++i)
      a[i] = *(const short8*)&As[(wm + i * 16 + m16) * 40 + quad * 8];
#pragma unroll
    for (int j2 = 0; j2 < 4; ++j2)
      b[j2] = *(const short8*)&Bs[(wn + j2 * 16 + m16) * 40 + quad * 8];
#pragma unroll
    for (int i = 0; i < 2; ++i)
#pragma unroll
      for (int j2 = 0; j2 < 4; ++j2)
        acc[i][j2] = __builtin_amdgcn_mfma_f32_16x16x32_bf16(a[i], b[j2], acc[i][j2], 0, 0, 0);
    __syncthreads();
  }

  // epilogue: C/D layout col=lane&15, row=quad*4+r (m89/m91)
  float bv[4]; int bcol[4];
#pragma unroll
  for (int j2 = 0; j2 < 4; ++j2) {
    bcol[j2] = bn + wn + j2 * 16 + m16;
    bv[j2] = d.bias[bcol[j2]];
  }
#pragma unroll
  for (int i = 0; i < 2; ++i) {
    const int rbase = bm + wm + i * 16 + quad * 4;
#pragma unroll
    for (int r = 0; r < 4; ++r) {
      const int row = rbase + r;
      if (row < d.M) {
#pragma unroll
        for (int j2 = 0; j2 < 4; ++j2)
          d.C[(size_t)row * DMODEL + bcol[j2]] = acc[i][j2][r] + bv[j2];
      }
    }
  }
}

// Output GEMM: A bf16 [M,768] @ W^T + bias -> f32. Same tile/swizzle as above.
// NB (R10 post-mortem): A staging is 8 bf16 = 16 B per thread -> uint4.
// The uint2 version staged only half the tile and left garbage LDS -> NaN.
__global__ __launch_bounds__(256) void gemm_mfma_out(const unsigned short* __restrict__ Ab,
    const unsigned short* __restrict__ Wb, const float* __restrict__ bias,
    float* __restrict__ C, int M) {
  __shared__ unsigned short As[64 * 40];
  __shared__ unsigned short Bs[128 * 40];
  const int t = threadIdx.x;
  const int id = blockIdx.x;
  const int xcd = id & 7, j = id >> 3;
  const int bn = (j % 6) * 128;
  const int bm = ((j / 6) * 8 + xcd) * 64;
  const int lane = t & 63, wid = t >> 6;
  const int m16 = lane & 15, quad = lane >> 4;
  const int wm = (wid & 1) * 32, wn = (wid >> 1) * 64;

  f32x4 acc[2][4];
#pragma unroll
  for (int i = 0; i < 2; ++i)
#pragma unroll
    for (int j2 = 0; j2 < 4; ++j2) acc[i][j2] = (f32x4){0.f, 0.f, 0.f, 0.f};

  const int srowA = t >> 2, skcA = (t & 3) * 8;
  const int srowB = t >> 1, skcB = (t & 1) * 16;
  const int am = bm + srowA;
  const bool amok = am < M;
  const int wrow = bn + srowB;

  for (int k0 = 0; k0 < DMODEL; k0 += 32) {
    uint4 aw;
    if (amok) aw = *(const uint4*)(Ab + (size_t)am * DMODEL + k0 + skcA);
    else      aw = make_uint4(0, 0, 0, 0);
    const uint4* pw = (const uint4*)(Wb + (size_t)wrow * DMODEL + k0 + skcB);
    uint4 w0 = pw[0], w1 = pw[1];
    *(uint4*)&As[srowA * 40 + skcA]     = aw;
    *(uint4*)&Bs[srowB * 40 + skcB]     = w0;
    *(uint4*)&Bs[srowB * 40 + skcB + 8] = w1;
    __syncthreads();
    short8 a[2], b[4];
#pragma unroll
    for (int i = 0; i < 2; ++i)
      a[i] = *(const short8*)&As[(wm + i * 16 + m16) * 40 + quad * 8];
#pragma unroll
    for (int j2 = 0; j2 < 4; ++j2)
      b[j2] = *(const short8*)&Bs[(wn + j2 * 16 + m16) * 40 + quad * 8];
#pragma unroll
    for (int i = 0; i < 2; ++i)
#pragma unroll
      for (int j2 = 0; j2 < 4; ++j2)
        acc[i][j2] = __builtin_amdgcn_mfma_f32_16x16x32_bf16(a[i], b[j2], acc[i][j2], 0, 0, 0);
    __syncthreads();
  }

  float bv[4]; int bcol[4];
#pragma unroll
  for (int j2 = 0; j2 < 4; ++j2) {
    bcol[j2] = bn + wn + j2 * 16 + m16;
    bv[j2] = bias[bcol[j2]];
  }
#pragma unroll
  for (int i = 0; i < 2; ++i) {
    const int rbase = bm + wm + i * 16 + quad * 4;
#pragma unroll
    for (int r = 0; r < 4; ++r) {
      const int row = rbase + r;
      if (row < M) {
#pragma unroll
        for (int j2 = 0; j2 < 4; ++j2)
          C[(size_t)row * DMODEL + bcol[j2]] = acc[i][j2][r] + bv[j2];
      }
    }
  }
}

// one block: prefix-scan query_mask -> left/right/nvalid per feature,
// plus compact list of fully-masked features (nvalid==0).
__global__ __launch_bounds__(1024) void build_segments(const int* __restrict__ qm,
    const int* __restrict__ ids, const int* __restrict__ padp,
    int n, int f, int* __restrict__ left, int* __restrict__ right,
    int* __restrict__ nvalid, int* __restrict__ fullrank,
    int* __restrict__ fullist, int* __restrict__ nfull) {
  __shared__ int cnt[1024];
  __shared__ int fullcnt;
  const int t = threadIdx.x;
  if (t == 0) fullcnt = 0;
  const int per = (n + 1023) >> 10;
  const int base = t * per;
  int c = 0;
  for (int i = 0; i < per; ++i) {
    int p = base + i;
    if (p < n && qm[p] != 0) ++c;
  }
  cnt[t] = c;
  __syncthreads();
  for (int off = 1; off < 1024; off <<= 1) {
    int v = (t >= off) ? cnt[t - off] : 0;
    __syncthreads();
    cnt[t] += v;
    __syncthreads();
  }
  int r = cnt[t] - c;  // exclusive prefix
  for (int i = 0; i < per; ++i) {
    int p = base + i;
    if (p < n && qm[p] != 0) {
      if (r < f) left[r] = p;
      ++r;
    }
  }
  __syncthreads();
  const int pad = *padp;
  for (int i = t; i < f; i += 1024) {
    int L0 = left[i];
    int R0 = (i + 1 < f) ? left[i + 1] : n;
    right[i] = R0;
    int cv = 0;
    for (int p = L0; p < R0; ++p) cv += (ids[p] != pad) ? 1 : 0;
    nvalid[i] = cv;
    if (cv == 0) {
      int rk = atomicAdd(&fullcnt, 1);
      if (rk < MAXFULL) { fullist[rk] = i; fullrank[i] = rk; }
      else fullrank[i] = -1;
    } else {
      fullrank[i] = -1;
    }
  }
  __syncthreads();
  if (t == 0) *nfull = (fullcnt < MAXFULL) ? fullcnt : MAXFULL;
}

__device__ __forceinline__ float allreduce64(float x) {
#pragma unroll
  for (int m = 1; m < 64; m <<= 1) x += __shfl_xor(x, m, 64);
  return x;
}

// normal features: online softmax over the (short) segment, skipping pad keys.
// Out-of-segment/pad contributions underflow to exact 0 in the reference's f32
// softmax, so segment-only is exact. Writes bf16 (input to the Wo GEMM).
__global__ __launch_bounds__(64) void attn_seg(const float* __restrict__ q,
    const float* __restrict__ k, const float* __restrict__ v,
    const int* __restrict__ left, const int* __restrict__ right,
    const int* __restrict__ nvalid, const int* __restrict__ ids,
    const int* __restrict__ padp, unsigned short* __restrict__ out) {
  const int feat = blockIdx.x, h = blockIdx.y, lane = threadIdx.x;
  if (nvalid[feat] == 0) return;  // handled by attn_full_*
  const int off = h * 64 + lane;
  const int pad = *padp;
  const float qv = q[(size_t)feat * DMODEL + off];
  float m = -1e30f, l = 0.f, acc = 0.f;
  const int L0 = left[feat], R0 = right[feat];
  for (int p = L0; p < R0; ++p) {
    if (ids[p] == pad) continue;
    float s = allreduce64(qv * k[(size_t)p * DMODEL + off]) * 0.125f;
    float mn = fmaxf(m, s);
    float al = __expf(m - mn);
    float w = __expf(s - mn);
    l = l * al + w;
    acc = acc * al + w * v[(size_t)p * DMODEL + off];
    m = mn;
  }
  out[(size_t)feat * DMODEL + off] = bf16_1(acc / l);
}

// fully-masked features: uniform -10000 bias cancels in softmax -> full softmax
// over ALL n keys (pads included, cross-batch).
// One wave per (head, 64-key piece); lane=key for QK (streamed in-lane dot vs
// all q's staged in LDS), lane=dim for PV (weights via aligned LDS b128).
__global__ __launch_bounds__(256) void attn_full_part(const float* __restrict__ q,
    const float* __restrict__ k, const float* __restrict__ v,
    const int* __restrict__ fullist, const int* __restrict__ nfullp,
    int n, int P, float* __restrict__ pm, float* __restrict__ pl,
    float* __restrict__ pacc) {
  const int nfull = *nfullp;
  if (nfull == 0) return;
  const int t = threadIdx.x, lane = t & 63, wv = t >> 6;
  const int gw = blockIdx.x * 4 + wv;     // P % 4 == 0 -> block-uniform head
  const int h = gw / P, piece = gw - h * P;
  const int pk = n / P;                    // keys per piece (multiple of 64)

  __shared__ float q_lds[8 * 64];
  __shared__ float w_lds[4][64 * 8];       // [wave][key][feat], 32B-aligned rows

  for (int idx = t; idx < 8 * 64; idx += 256) {
    int fl = idx >> 6, d = idx & 63;
    q_lds[idx] = (fl < nfull) ? q[(size_t)fullist[fl] * DMODEL + h * 64 + d] : 0.f;
  }
  __syncthreads();

  float m[8], l[8], acc[8];
#pragma unroll
  for (int f_ = 0; f_ < 8; ++f_) { m[f_] = -1e30f; l[f_] = 0.f; acc[f_] = 0.f; }

  for (int c = 0; c < pk; c += 64) {
    const int pc = piece * pk + c;
    // ---- phase A: lane = key. Stream k in two 8-float4 groups (no kv[16]).
    float s[8];
#pragma unroll
    for (int f_ = 0; f_ < 8; ++f_) s[f_] = 0.f;
    const float4* kp = (const float4*)(k + (size_t)(pc + lane) * DMODEL + h * 64);
#pragma unroll 1
    for (int g = 0; g < 2; ++g) {
      float4 kv0 = kp[g * 8 + 0], kv1 = kp[g * 8 + 1], kv2 = kp[g * 8 + 2],
             kv3 = kp[g * 8 + 3], kv4 = kp[g * 8 + 4], kv5 = kp[g * 8 + 5],
             kv6 = kp[g * 8 + 6], kv7 = kp[g * 8 + 7];
      const float4* qb = (const float4*)&q_lds[g * 32];
#pragma unroll
      for (int f_ = 0; f_ < 8; ++f_) {
        float4 q0 = qb[f_ * 16 + 0], q1 = qb[f_ * 16 + 1], q2 = qb[f_ * 16 + 2],
               q3 = qb[f_ * 16 + 3], q4 = qb[f_ * 16 + 4], q5 = qb[f_ * 16 + 5],
               q6 = qb[f_ * 16 + 6], q7 = qb[f_ * 16 + 7];
        float acc0 = q0.x * kv0.x + q0.y * kv0.y + q0.z * kv0.z + q0.w * kv0.w;
        acc0 += q1.x * kv1.x + q1.y * kv1.y + q1.z * kv1.z + q1.w * kv1.w;
        acc0 += q2.x * kv2.x + q2.y * kv2.y + q2.z * kv2.z + q2.w * kv2.w;
        acc0 += q3.x * kv3.x + q3.y * kv3.y + q3.z * kv3.z + q3.w * kv3.w;
        acc0 += q4.x * kv4.x + q4.y * kv4.y + q4.z * kv4.z + q4.w * kv4.w;
        acc0 += q5.x * kv5.x + q5.y * kv5.y + q5.z * kv5.z + q5.w * kv5.w;
        acc0 += q6.x * kv6.x + q6.y * kv6.y + q6.z * kv6.z + q6.w * kv6.w;
        acc0 += q7.x * kv7.x + q7.y * kv7.y + q7.z * kv7.z + q7.w * kv7.w;
        s[f_] += acc0;
      }
    }
    // batched reductions: 8 independent chains interleave per step
    float mx[8];
#pragma unroll
    for (int f_ = 0; f_ < 8; ++f_) mx[f_] = s[f_] * 0.125f;
#pragma unroll
    for (int f_ = 0; f_ < 8; ++f_) s[f_] = mx[f_];
#pragma unroll
    for (int st = 1; st < 64; st <<= 1)
#pragma unroll
      for (int f_ = 0; f_ < 8; ++f_) mx[f_] = fmaxf(mx[f_], __shfl_xor(mx[f_], st, 64));
    float alpha[8], w[8], sum[8];
#pragma unroll
    for (int f_ = 0; f_ < 8; ++f_) {
      float mn = fmaxf(m[f_], mx[f_]);
      alpha[f_] = __expf(m[f_] - mn);
      w[f_] = __expf(s[f_] - mn);
      m[f_] = mn;
      sum[f_] = w[f_];
    }
#pragma unroll
    for (int st = 1; st < 64; st <<= 1)
#pragma unroll
      for (int f_ = 0; f_ < 8; ++f_) sum[f_] += __shfl_xor(sum[f_], st, 64);
#pragma unroll
    for (int f_ = 0; f_ < 8; ++f_) l[f_] = l[f_] * alpha[f_] + sum[f_];
    // two aligned b128 stores (intra-wave LDS: hw orders ds ops in program order)
    *(float4*)&w_lds[wv][lane * 8]     = make_float4(w[0], w[1], w[2], w[3]);
    *(float4*)&w_lds[wv][lane * 8 + 4] = make_float4(w[4], w[5], w[6], w[7]);
    // ---- phase B: lane = dim
#pragma unroll
    for (int f_ = 0; f_ < 8; ++f_) acc[f_] *= alpha[f_];
    const float* vb = v + (size_t)pc * DMODEL + h * 64 + lane;
#pragma unroll 4
    for (int kk = 0; kk < 64; ++kk) {
      float vd = vb[(size_t)kk * DMODEL];
      float4 wa = *(const float4*)&w_lds[wv][kk * 8];      // broadcast b128
      float4 wb = *(const float4*)&w_lds[wv][kk * 8 + 4];
      acc[0] += wa.x * vd; acc[1] += wa.y * vd; acc[2] += wa.z * vd; acc[3] += wa.w * vd;
      acc[4] += wb.x * vd; acc[5] += wb.y * vd; acc[6] += wb.z * vd; acc[7] += wb.w * vd;
    }
  }

  for (int f_ = 0; f_ < nfull; ++f_) {
    size_t idx = ((size_t)f_ * NHEADS + h) * P + piece;
    if (lane == 0) { pm[idx] = m[f_]; pl[idx] = l[f_]; }
    pacc[idx * 64 + lane] = acc[f_];
  }
}

// Split-K pass 2: merge the P partials per (full-feature, head).
// One block (256 thr) per (fl, h): parallel block reductions. Writes bf16.
__global__ __launch_bounds__(256) void attn_full_comb(
    const int* __restrict__ fullist, const int* __restrict__ nfullp,
    int P, const float* __restrict__ pm, const float* __restrict__ pl,
    const float* __restrict__ pacc, unsigned short* __restrict__ out) {
  const int fl = blockIdx.x, h = blockIdx.y;
  if (fl >= *nfullp) return;
  const int feat = fullist[fl];
  const int t = threadIdx.x, lane = t & 63, wv = t >> 6;
  const size_t base = ((size_t)fl * NHEADS + h) * P;

  __shared__ float s_pm[128];    // P <= 128
  __shared__ float s_sc[128];
  __shared__ float s_red[4];
  __shared__ float s_part[4][64];

  for (int sp = t; sp < P; sp += 256) s_pm[sp] = pm[base + sp];
  __syncthreads();
  // block max of pm
  float mloc = -1e30f;
  for (int sp = t; sp < P; sp += 256) mloc = fmaxf(mloc, s_pm[sp]);
#pragma unroll
  for (int st = 1; st < 64; st <<= 1) mloc = fmaxf(mloc, __shfl_xor(mloc, st, 64));
  if (lane == 0) s_red[wv] = mloc;
  __syncthreads();
  const float M = fmaxf(fmaxf(s_red[0], s_red[1]), fmaxf(s_red[2], s_red[3]));
  __syncthreads();  // everyone has M before s_red reuse
  // scale factors + Lt
  float lloc = 0.f;
  for (int sp = t; sp < P; sp += 256) {
    float sc = __expf(s_pm[sp] - M);
    s_sc[sp] = sc;
    lloc += pl[base + sp] * sc;
  }
#pragma unroll
  for (int st = 1; st < 64; st <<= 1) lloc += __shfl_xor(lloc, st, 64);
  if (lane == 0) s_red[wv] = lloc;
  __syncthreads();
  const float Lt = s_red[0] + s_red[1] + s_red[2] + s_red[3];
  // weighted acc: wave wv takes sp = wv, wv+4, ... (independent coalesced loads)
  float At = 0.f;
  for (int sp = wv; sp < P; sp += 4)
    At += pacc[(base + sp) * 64 + lane] * s_sc[sp];
  s_part[wv][lane] = At;
  __syncthreads();
  if (wv == 0) {
    float tot = s_part[0][lane] + s_part[1][lane] + s_part[2][lane] + s_part[3][lane];
    out[(size_t)feat * DMODEL + h * 64 + lane] = bf16_1(tot / Lt);
  }
}

extern "C" void kernel_launch(void* const* d_in, const int* in_sizes, int n_in,
                              void* d_out, int out_size, void* d_ws, size_t ws_size,
                              hipStream_t stream) {
  const float* x_qk = (const float*)d_in[0];
  const float* x_v  = (const float*)d_in[1];
  const int* qm     = (const int*)d_in[2];
  const int* ids    = (const int*)d_in[3];
  const int* padp   = (const int*)d_in[4];
  const float* Wq = (const float*)d_in[5];
  const float* bq = (const float*)d_in[6];
  const float* Wk = (const float*)d_in[7];
  const float* bk = (const float*)d_in[8];
  const float* Wv = (const float*)d_in[9];
  const float* bv = (const float*)d_in[10];
  const float* Wo = (const float*)d_in[11];
  const float* bo = (const float*)d_in[12];

  const int n = in_sizes[0] / DMODEL;   // 8192
  const int f = out_size / DMODEL;      // 1024

  // ws layout: kf,vf,qf f32 | af bf16 | Wbf x4 | ints | split partials
  float* kf = (float*)d_ws;
  float* vf = kf + (size_t)n * DMODEL;
  float* qf = vf + (size_t)n * DMODEL;
  unsigned short* af = (unsigned short*)(qf + (size_t)f * DMODEL);
  unsigned short* wqb = af + (size_t)f * DMODEL;
  unsigned short* wkb = wqb + DMODEL * DMODEL;
  unsigned short* wvb = wkb + DMODEL * DMODEL;
  unsigned short* wob = wvb + DMODEL * DMODEL;
  int* left     = (int*)(wob + DMODEL * DMODEL);
  int* right    = left + f;
  int* nvalid   = right + f;
  int* fullrank = nvalid + f;
  int* fullist  = fullrank + f;
  int* nfull    = fullist + MAXFULL;
  size_t off_bytes = ((size_t)((char*)(nfull + 1) - (char*)d_ws) + 255) & ~(size_t)255;
  // pieces of 64 keys each: P waves per head; pk = n/P must be a multiple of 64
  int P = 128;
  while (P > 16) {
    size_t need = (size_t)MAXFULL * NHEADS * P * 66 * sizeof(float);
    if (off_bytes + need <= ws_size && (n / P) % 64 == 0 && n % P == 0) break;
    P >>= 1;
  }
  float* pm = (float*)((char*)d_ws + off_bytes);
  float* pl = pm + (size_t)MAXFULL * NHEADS * P;
  float* pacc = pl + (size_t)MAXFULL * NHEADS * P;

  build_segments<<<1, 1024, 0, stream>>>(qm, ids, padp, n, f, left, right,
                                         nvalid, fullrank, fullist, nfull);
  convW<<<1152, 256, 0, stream>>>(Wq, Wk, Wv, Wo, (unsigned*)wqb, (unsigned*)wkb,
                                  (unsigned*)wvb, (unsigned*)wob, DMODEL * DMODEL);

  const int TKV = 6 * (n / 64);   // 768 blocks/segment, (n/64)%8==0
  const int TF  = 6 * (f / 64);   // 96 blocks, (f/64)%8==0
  GDesc g0 = { x_qk, wkb, bk, nullptr, kf, n, 0 };
  GDesc g1 = { x_v,  wvb, bv, nullptr, vf, n, TKV };
  GDesc g2 = { x_qk, wqb, bq, left,    qf, f, 2 * TKV };
  gemm_mfma3<<<2 * TKV + TF, 256, 0, stream>>>(g0, g1, g2);

  attn_seg<<<dim3(f, NHEADS), 64, 0, stream>>>(qf, kf, vf, left, right, nvalid,
                                               ids, padp, af);
  attn_full_part<<<NHEADS * P / 4, 256, 0, stream>>>(qf, kf, vf, fullist, nfull,
                                                     n, P, pm, pl, pacc);
  attn_full_comb<<<dim3(MAXFULL, NHEADS), 256, 0, stream>>>(fullist, nfull, P,
                                                            pm, pl, pacc, af);

  gemm_mfma_out<<<TF, 256, 0, stream>>>(af, wob, bo, (float*)d_out, f);
}

// Round 12
// 233.291 us; speedup vs baseline: 1.3781x; 1.0376x over previous
//
#include <hip/hip_runtime.h>

#define DMODEL 768
#define NHEADS 12
#define MAXFULL 16

typedef __attribute__((ext_vector_type(8))) short short8;
typedef __attribute__((ext_vector_type(4))) float f32x4;

__device__ __forceinline__ unsigned pack2_bf16(float a, float b) {
  unsigned ua = __float_as_uint(a), ub = __float_as_uint(b);
  ua = (ua + 0x7fffu + ((ua >> 16) & 1u)) >> 16;
  ub = (ub + 0x7fffu + ((ub >> 16) & 1u)) & 0xffff0000u;
  return ua | ub;
}
__device__ __forceinline__ unsigned short bf16_1(float a) {
  unsigned ua = __float_as_uint(a);
  return (unsigned short)((ua + 0x7fffu + ((ua >> 16) & 1u)) >> 16);
}

// direct global->LDS DMA, 16 B per lane; LDS dest = wave-uniform base + lane*16
__device__ __forceinline__ void load16_lds(const void* g, void* l) {
  __builtin_amdgcn_global_load_lds(
      (const __attribute__((address_space(1))) unsigned int*)g,
      (__attribute__((address_space(3))) unsigned int*)l, 16, 0, 0);
}

// convert the 4 weight matrices f32 -> bf16 once
__global__ __launch_bounds__(256) void convW(const float* __restrict__ w0,
    const float* __restrict__ w1, const float* __restrict__ w2,
    const float* __restrict__ w3, unsigned* __restrict__ o0,
    unsigned* __restrict__ o1, unsigned* __restrict__ o2,
    unsigned* __restrict__ o3, int count) {
  const int nv = count >> 2;
  const float* src[4] = {w0, w1, w2, w3};
  unsigned* dst[4] = {o0, o1, o2, o3};
  for (int idx = blockIdx.x * 256 + threadIdx.x; idx < 4 * nv;
       idx += gridDim.x * 256) {
    int m = idx / nv, r = idx - m * nv;
    float4 v = ((const float4*)src[m])[r];
    dst[m][2 * r]     = pack2_bf16(v.x, v.y);
    dst[m][2 * r + 1] = pack2_bf16(v.z, v.w);
  }
}

// convert x_qk, x_v f32 -> bf16 once (removes pack VALU from the GEMM K-loop
// and halves A HBM bytes; enables global_load_lds staging — m97 recipe)
__global__ __launch_bounds__(256) void convX(const float* __restrict__ x0,
    const float* __restrict__ x1, unsigned* __restrict__ o0,
    unsigned* __restrict__ o1, int count) {
  const int nv = count >> 2;
  for (int idx = blockIdx.x * 256 + threadIdx.x; idx < 2 * nv;
       idx += gridDim.x * 256) {
    int m = idx / nv, r = idx - m * nv;
    float4 v = m ? ((const float4*)x1)[r] : ((const float4*)x0)[r];
    unsigned* d = m ? o1 : o0;
    d[2 * r]     = pack2_bf16(v.x, v.y);
    d[2 * r + 1] = pack2_bf16(v.z, v.w);
  }
}

struct GSeg {
  const unsigned short* A;   // bf16 activations [*,768]
  const unsigned short* W;   // bf16 weights [col][k]
  const float* bias;
  const int* row_map;        // optional row gather
  float* C;                  // f32 out
  int base;                  // first flat block id of this segment (mult of 8)
};

// m97-style GEMM, up to 3 fused segments: 128x128 tile, BK=32, 4 waves x
// (4x4 16x16x32 frags), global_load_lds width-16 staging into unpadded LDS
// (the __syncthreads vmcnt(0)+lgkmcnt(0) drain covers DMA completion), XCD
// swizzle for L2 locality. M per segment must be a multiple of 128 and
// (M/128) % 8 == 0 ... or == tile count covered by (xcd, j) exactly.
__global__ __launch_bounds__(256) void gemm128(GSeg g0, GSeg g1, GSeg g2) {
  __shared__ __attribute__((aligned(16))) unsigned short As[128 * 32];
  __shared__ __attribute__((aligned(16))) unsigned short Bs[128 * 32];
  const int t = threadIdx.x;
  const int id = blockIdx.x;
  const GSeg& d = (id >= g2.base) ? g2 : ((id >= g1.base) ? g1 : g0);
  const int lid = id - d.base;
  const int xcd = lid & 7, j = lid >> 3;
  const int bn = (j % 6) * 128;
  const int bm = ((j / 6) * 8 + xcd) * 128;
  const int lane = t & 63, wid = t >> 6;
  const int m16 = lane & 15, quad = lane >> 4;
  const int wm = (wid >> 1) * 64, wn = (wid & 1) * 64;

  f32x4 acc[4][4];
#pragma unroll
  for (int i = 0; i < 4; ++i)
#pragma unroll
    for (int j2 = 0; j2 < 4; ++j2) acc[i][j2] = (f32x4){0.f, 0.f, 0.f, 0.f};

  // staging: wave wid covers tile rows [wid*32, wid*32+32), 16 rows per issue,
  // lane covers row +lane/4, k-chunk (lane&3)*8 elems (16 B)
  const int srow = wid * 32 + (lane >> 2);
  const int skc = (lane & 3) * 8;
  int arow0, arow1;
  if (d.row_map) {
    arow0 = d.row_map[bm + srow];
    arow1 = d.row_map[bm + srow + 16];
  } else {
    arow0 = bm + srow;
    arow1 = bm + srow + 16;
  }
  const int wrow0 = bn + srow, wrow1 = bn + srow + 16;
  unsigned short* As0 = &As[(wid * 32) * 32];
  unsigned short* As1 = &As[(wid * 32 + 16) * 32];
  unsigned short* Bs0 = &Bs[(wid * 32) * 32];
  unsigned short* Bs1 = &Bs[(wid * 32 + 16) * 32];

  for (int k0 = 0; k0 < DMODEL; k0 += 32) {
    load16_lds(d.A + (size_t)arow0 * DMODEL + k0 + skc, As0);
    load16_lds(d.A + (size_t)arow1 * DMODEL + k0 + skc, As1);
    load16_lds(d.W + (size_t)wrow0 * DMODEL + k0 + skc, Bs0);
    load16_lds(d.W + (size_t)wrow1 * DMODEL + k0 + skc, Bs1);
    __syncthreads();   // drains vmcnt(0): DMA complete for all waves
    short8 a[4], b[4];
#pragma unroll
    for (int i = 0; i < 4; ++i)
      a[i] = *(const short8*)&As[(wm + i * 16 + m16) * 32 + quad * 8];
#pragma unroll
    for (int j2 = 0; j2 < 4; ++j2)
      b[j2] = *(const short8*)&Bs[(wn + j2 * 16 + m16) * 32 + quad * 8];
#pragma unroll
    for (int i = 0; i < 4; ++i)
#pragma unroll
      for (int j2 = 0; j2 < 4; ++j2)
        acc[i][j2] = __builtin_amdgcn_mfma_f32_16x16x32_bf16(a[i], b[j2], acc[i][j2], 0, 0, 0);
    __syncthreads();
  }

  // epilogue: C/D layout col=lane&15, row=quad*4+r (m89/m91)
  float bv[4]; int bcol[4];
#pragma unroll
  for (int j2 = 0; j2 < 4; ++j2) {
    bcol[j2] = bn + wn + j2 * 16 + m16;
    bv[j2] = d.bias[bcol[j2]];
  }
#pragma unroll
  for (int i = 0; i < 4; ++i) {
    const int rbase = bm + wm + i * 16 + quad * 4;
#pragma unroll
    for (int r = 0; r < 4; ++r) {
      const int row = rbase + r;
#pragma unroll
      for (int j2 = 0; j2 < 4; ++j2)
        d.C[(size_t)row * DMODEL + bcol[j2]] = acc[i][j2][r] + bv[j2];
    }
  }
}

// one block: prefix-scan query_mask -> left/right/nvalid per feature,
// plus compact list of fully-masked features (nvalid==0).
__global__ __launch_bounds__(1024) void build_segments(const int* __restrict__ qm,
    const int* __restrict__ ids, const int* __restrict__ padp,
    int n, int f, int* __restrict__ left, int* __restrict__ right,
    int* __restrict__ nvalid, int* __restrict__ fullrank,
    int* __restrict__ fullist, int* __restrict__ nfull) {
  __shared__ int cnt[1024];
  __shared__ int fullcnt;
  const int t = threadIdx.x;
  if (t == 0) fullcnt = 0;
  const int per = (n + 1023) >> 10;
  const int base = t * per;
  int c = 0;
  for (int i = 0; i < per; ++i) {
    int p = base + i;
    if (p < n && qm[p] != 0) ++c;
  }
  cnt[t] = c;
  __syncthreads();
  for (int off = 1; off < 1024; off <<= 1) {
    int v = (t >= off) ? cnt[t - off] : 0;
    __syncthreads();
    cnt[t] += v;
    __syncthreads();
  }
  int r = cnt[t] - c;  // exclusive prefix
  for (int i = 0; i < per; ++i) {
    int p = base + i;
    if (p < n && qm[p] != 0) {
      if (r < f) left[r] = p;
      ++r;
    }
  }
  __syncthreads();
  const int pad = *padp;
  for (int i = t; i < f; i += 1024) {
    int L0 = left[i];
    int R0 = (i + 1 < f) ? left[i + 1] : n;
    right[i] = R0;
    int cv = 0;
    for (int p = L0; p < R0; ++p) cv += (ids[p] != pad) ? 1 : 0;
    nvalid[i] = cv;
    if (cv == 0) {
      int rk = atomicAdd(&fullcnt, 1);
      if (rk < MAXFULL) { fullist[rk] = i; fullrank[i] = rk; }
      else fullrank[i] = -1;
    } else {
      fullrank[i] = -1;
    }
  }
  __syncthreads();
  if (t == 0) *nfull = (fullcnt < MAXFULL) ? fullcnt : MAXFULL;
}

__device__ __forceinline__ float allreduce64(float x) {
#pragma unroll
  for (int m = 1; m < 64; m <<= 1) x += __shfl_xor(x, m, 64);
  return x;
}

// normal features: online softmax over the (short) segment, skipping pad keys.
// Out-of-segment/pad contributions underflow to exact 0 in the reference's f32
// softmax, so segment-only is exact. Writes bf16 (input to the Wo GEMM).
__global__ __launch_bounds__(64) void attn_seg(const float* __restrict__ q,
    const float* __restrict__ k, const float* __restrict__ v,
    const int* __restrict__ left, const int* __restrict__ right,
    const int* __restrict__ nvalid, const int* __restrict__ ids,
    const int* __restrict__ padp, unsigned short* __restrict__ out) {
  const int feat = blockIdx.x, h = blockIdx.y, lane = threadIdx.x;
  if (nvalid[feat] == 0) return;  // handled by attn_full_*
  const int off = h * 64 + lane;
  const int pad = *padp;
  const float qv = q[(size_t)feat * DMODEL + off];
  float m = -1e30f, l = 0.f, acc = 0.f;
  const int L0 = left[feat], R0 = right[feat];
  for (int p = L0; p < R0; ++p) {
    if (ids[p] == pad) continue;
    float s = allreduce64(qv * k[(size_t)p * DMODEL + off]) * 0.125f;
    float mn = fmaxf(m, s);
    float al = __expf(m - mn);
    float w = __expf(s - mn);
    l = l * al + w;
    acc = acc * al + w * v[(size_t)p * DMODEL + off];
    m = mn;
  }
  out[(size_t)feat * DMODEL + off] = bf16_1(acc / l);
}

// fully-masked features: uniform -10000 bias cancels in softmax -> full softmax
// over ALL n keys (pads included, cross-batch).
__global__ __launch_bounds__(256) void attn_full_part(const float* __restrict__ q,
    const float* __restrict__ k, const float* __restrict__ v,
    const int* __restrict__ fullist, const int* __restrict__ nfullp,
    int n, int P, float* __restrict__ pm, float* __restrict__ pl,
    float* __restrict__ pacc) {
  const int nfull = *nfullp;
  if (nfull == 0) return;
  const int t = threadIdx.x, lane = t & 63, wv = t >> 6;
  const int gw = blockIdx.x * 4 + wv;     // P % 4 == 0 -> block-uniform head
  const int h = gw / P, piece = gw - h * P;
  const int pk = n / P;                    // keys per piece (multiple of 64)

  __shared__ float q_lds[8 * 64];
  __shared__ float w_lds[4][64 * 8];       // [wave][key][feat], 32B-aligned rows

  for (int idx = t; idx < 8 * 64; idx += 256) {
    int fl = idx >> 6, d = idx & 63;
    q_lds[idx] = (fl < nfull) ? q[(size_t)fullist[fl] * DMODEL + h * 64 + d] : 0.f;
  }
  __syncthreads();

  float m[8], l[8], acc[8];
#pragma unroll
  for (int f_ = 0; f_ < 8; ++f_) { m[f_] = -1e30f; l[f_] = 0.f; acc[f_] = 0.f; }

  for (int c = 0; c < pk; c += 64) {
    const int pc = piece * pk + c;
    float s[8];
#pragma unroll
    for (int f_ = 0; f_ < 8; ++f_) s[f_] = 0.f;
    const float4* kp = (const float4*)(k + (size_t)(pc + lane) * DMODEL + h * 64);
#pragma unroll 1
    for (int g = 0; g < 2; ++g) {
      float4 kv0 = kp[g * 8 + 0], kv1 = kp[g * 8 + 1], kv2 = kp[g * 8 + 2],
             kv3 = kp[g * 8 + 3], kv4 = kp[g * 8 + 4], kv5 = kp[g * 8 + 5],
             kv6 = kp[g * 8 + 6], kv7 = kp[g * 8 + 7];
      const float4* qb = (const float4*)&q_lds[g * 32];
#pragma unroll
      for (int f_ = 0; f_ < 8; ++f_) {
        float4 q0 = qb[f_ * 16 + 0], q1 = qb[f_ * 16 + 1], q2 = qb[f_ * 16 + 2],
               q3 = qb[f_ * 16 + 3], q4 = qb[f_ * 16 + 4], q5 = qb[f_ * 16 + 5],
               q6 = qb[f_ * 16 + 6], q7 = qb[f_ * 16 + 7];
        float acc0 = q0.x * kv0.x + q0.y * kv0.y + q0.z * kv0.z + q0.w * kv0.w;
        acc0 += q1.x * kv1.x + q1.y * kv1.y + q1.z * kv1.z + q1.w * kv1.w;
        acc0 += q2.x * kv2.x + q2.y * kv2.y + q2.z * kv2.z + q2.w * kv2.w;
        acc0 += q3.x * kv3.x + q3.y * kv3.y + q3.z * kv3.z + q3.w * kv3.w;
        acc0 += q4.x * kv4.x + q4.y * kv4.y + q4.z * kv4.z + q4.w * kv4.w;
        acc0 += q5.x * kv5.x + q5.y * kv5.y + q5.z * kv5.z + q5.w * kv5.w;
        acc0 += q6.x * kv6.x + q6.y * kv6.y + q6.z * kv6.z + q6.w * kv6.w;
        acc0 += q7.x * kv7.x + q7.y * kv7.y + q7.z * kv7.z + q7.w * kv7.w;
        s[f_] += acc0;
      }
    }
    float mx[8];
#pragma unroll
    for (int f_ = 0; f_ < 8; ++f_) mx[f_] = s[f_] * 0.125f;
#pragma unroll
    for (int f_ = 0; f_ < 8; ++f_) s[f_] = mx[f_];
#pragma unroll
    for (int st = 1; st < 64; st <<= 1)
#pragma unroll
      for (int f_ = 0; f_ < 8; ++f_) mx[f_] = fmaxf(mx[f_], __shfl_xor(mx[f_], st, 64));
    float alpha[8], w[8], sum[8];
#pragma unroll
    for (int f_ = 0; f_ < 8; ++f_) {
      float mn = fmaxf(m[f_], mx[f_]);
      alpha[f_] = __expf(m[f_] - mn);
      w[f_] = __expf(s[f_] - mn);
      m[f_] = mn;
      sum[f_] = w[f_];
    }
#pragma unroll
    for (int st = 1; st < 64; st <<= 1)
#pragma unroll
      for (int f_ = 0; f_ < 8; ++f_) sum[f_] += __shfl_xor(sum[f_], st, 64);
#pragma unroll
    for (int f_ = 0; f_ < 8; ++f_) l[f_] = l[f_] * alpha[f_] + sum[f_];
    *(float4*)&w_lds[wv][lane * 8]     = make_float4(w[0], w[1], w[2], w[3]);
    *(float4*)&w_lds[wv][lane * 8 + 4] = make_float4(w[4], w[5], w[6], w[7]);
#pragma unroll
    for (int f_ = 0; f_ < 8; ++f_) acc[f_] *= alpha[f_];
    const float* vb = v + (size_t)pc * DMODEL + h * 64 + lane;
#pragma unroll 4
    for (int kk = 0; kk < 64; ++kk) {
      float vd = vb[(size_t)kk * DMODEL];
      float4 wa = *(const float4*)&w_lds[wv][kk * 8];
      float4 wb = *(const float4*)&w_lds[wv][kk * 8 + 4];
      acc[0] += wa.x * vd; acc[1] += wa.y * vd; acc[2] += wa.z * vd; acc[3] += wa.w * vd;
      acc[4] += wb.x * vd; acc[5] += wb.y * vd; acc[6] += wb.z * vd; acc[7] += wb.w * vd;
    }
  }

  for (int f_ = 0; f_ < nfull; ++f_) {
    size_t idx = ((size_t)f_ * NHEADS + h) * P + piece;
    if (lane == 0) { pm[idx] = m[f_]; pl[idx] = l[f_]; }
    pacc[idx * 64 + lane] = acc[f_];
  }
}

// Split-K pass 2: merge the P partials per (full-feature, head). Writes bf16.
__global__ __launch_bounds__(256) void attn_full_comb(
    const int* __restrict__ fullist, const int* __restrict__ nfullp,
    int P, const float* __restrict__ pm, const float* __restrict__ pl,
    const float* __restrict__ pacc, unsigned short* __restrict__ out) {
  const int fl = blockIdx.x, h = blockIdx.y;
  if (fl >= *nfullp) return;
  const int feat = fullist[fl];
  const int t = threadIdx.x, lane = t & 63, wv = t >> 6;
  const size_t base = ((size_t)fl * NHEADS + h) * P;

  __shared__ float s_pm[128];    // P <= 128
  __shared__ float s_sc[128];
  __shared__ float s_red[4];
  __shared__ float s_part[4][64];

  for (int sp = t; sp < P; sp += 256) s_pm[sp] = pm[base + sp];
  __syncthreads();
  float mloc = -1e30f;
  for (int sp = t; sp < P; sp += 256) mloc = fmaxf(mloc, s_pm[sp]);
#pragma unroll
  for (int st = 1; st < 64; st <<= 1) mloc = fmaxf(mloc, __shfl_xor(mloc, st, 64));
  if (lane == 0) s_red[wv] = mloc;
  __syncthreads();
  const float M = fmaxf(fmaxf(s_red[0], s_red[1]), fmaxf(s_red[2], s_red[3]));
  __syncthreads();
  float lloc = 0.f;
  for (int sp = t; sp < P; sp += 256) {
    float sc = __expf(s_pm[sp] - M);
    s_sc[sp] = sc;
    lloc += pl[base + sp] * sc;
  }
#pragma unroll
  for (int st = 1; st < 64; st <<= 1) lloc += __shfl_xor(lloc, st, 64);
  if (lane == 0) s_red[wv] = lloc;
  __syncthreads();
  const float Lt = s_red[0] + s_red[1] + s_red[2] + s_red[3];
  float At = 0.f;
  for (int sp = wv; sp < P; sp += 4)
    At += pacc[(base + sp) * 64 + lane] * s_sc[sp];
  s_part[wv][lane] = At;
  __syncthreads();
  if (wv == 0) {
    float tot = s_part[0][lane] + s_part[1][lane] + s_part[2][lane] + s_part[3][lane];
    out[(size_t)feat * DMODEL + h * 64 + lane] = bf16_1(tot / Lt);
  }
}

extern "C" void kernel_launch(void* const* d_in, const int* in_sizes, int n_in,
                              void* d_out, int out_size, void* d_ws, size_t ws_size,
                              hipStream_t stream) {
  const float* x_qk = (const float*)d_in[0];
  const float* x_v  = (const float*)d_in[1];
  const int* qm     = (const int*)d_in[2];
  const int* ids    = (const int*)d_in[3];
  const int* padp   = (const int*)d_in[4];
  const float* Wq = (const float*)d_in[5];
  const float* bq = (const float*)d_in[6];
  const float* Wk = (const float*)d_in[7];
  const float* bk = (const float*)d_in[8];
  const float* Wv = (const float*)d_in[9];
  const float* bv = (const float*)d_in[10];
  const float* Wo = (const float*)d_in[11];
  const float* bo = (const float*)d_in[12];

  const int n = in_sizes[0] / DMODEL;   // 8192
  const int f = out_size / DMODEL;      // 1024

  // ws: kf,vf,qf f32 | af bf16 | Wbf x4 | xqb,xvb bf16 | ints | split partials
  float* kf = (float*)d_ws;
  float* vf = kf + (size_t)n * DMODEL;
  float* qf = vf + (size_t)n * DMODEL;
  unsigned short* af = (unsigned short*)(qf + (size_t)f * DMODEL);
  unsigned short* wqb = af + (size_t)f * DMODEL;
  unsigned short* wkb = wqb + DMODEL * DMODEL;
  unsigned short* wvb = wkb + DMODEL * DMODEL;
  unsigned short* wob = wvb + DMODEL * DMODEL;
  unsigned short* xqb = wob + DMODEL * DMODEL;
  unsigned short* xvb = xqb + (size_t)n * DMODEL;
  int* left     = (int*)(xvb + (size_t)n * DMODEL);
  int* right    = left + f;
  int* nvalid   = right + f;
  int* fullrank = nvalid + f;
  int* fullist  = fullrank + f;
  int* nfull    = fullist + MAXFULL;
  size_t off_bytes = ((size_t)((char*)(nfull + 1) - (char*)d_ws) + 255) & ~(size_t)255;
  int P = 128;
  while (P > 16) {
    size_t need = (size_t)MAXFULL * NHEADS * P * 66 * sizeof(float);
    if (off_bytes + need <= ws_size && (n / P) % 64 == 0 && n % P == 0) break;
    P >>= 1;
  }
  float* pm = (float*)((char*)d_ws + off_bytes);
  float* pl = pm + (size_t)MAXFULL * NHEADS * P;
  float* pacc = pl + (size_t)MAXFULL * NHEADS * P;

  build_segments<<<1, 1024, 0, stream>>>(qm, ids, padp, n, f, left, right,
                                         nvalid, fullrank, fullist, nfull);
  convW<<<1152, 256, 0, stream>>>(Wq, Wk, Wv, Wo, (unsigned*)wqb, (unsigned*)wkb,
                                  (unsigned*)wvb, (unsigned*)wob, DMODEL * DMODEL);
  convX<<<2048, 256, 0, stream>>>(x_qk, x_v, (unsigned*)xqb, (unsigned*)xvb,
                                  n * DMODEL);

  const int TKV = 6 * (n / 128);   // 384 blocks/segment, (n/128)%8==0
  const int TF  = 6 * (f / 128);   // 48 blocks, f/128 == 8
  GSeg g0 = { xqb, wkb, bk, nullptr, kf, 0 };
  GSeg g1 = { xvb, wvb, bv, nullptr, vf, TKV };
  GSeg g2 = { xqb, wqb, bq, left,    qf, 2 * TKV };
  gemm128<<<2 * TKV + TF, 256, 0, stream>>>(g0, g1, g2);

  attn_seg<<<dim3(f, NHEADS), 64, 0, stream>>>(qf, kf, vf, left, right, nvalid,
                                               ids, padp, af);
  attn_full_part<<<NHEADS * P / 4, 256, 0, stream>>>(qf, kf, vf, fullist, nfull,
                                                     n, P, pm, pl, pacc);
  attn_full_comb<<<dim3(MAXFULL, NHEADS), 256, 0, stream>>>(fullist, nfull, P,
                                                            pm, pl, pacc, af);

  GSeg gout = { af, wob, bo, nullptr, (float*)d_out, 0 };
  GSeg gnull = { af, wob, bo, nullptr, (float*)d_out, 1 << 30 };
  gemm128<<<TF, 256, 0, stream>>>(gout, gnull, gnull);
}